// Round 1
// baseline (3127.268 us; speedup 1.0000x reference)
//
#include <hip/hip_runtime.h>
#include <hip/hip_cooperative_groups.h>

namespace cg = cooperative_groups;

#define CB 128     // batch
#define CF 1536    // feature
#define CE 512     // embed
#define CH 512     // hidden
#define CG 2048    // 4*H
#define CV 10000   // vocab
#define CT 40      // max len

// ---------------------------------------------------------------------------
// permute gate rows to interleaved layout: orig row g = q*512+j  ->  j*4+q
// also fold b_ih + b_hh into one bias vector (added once into xg)
// ---------------------------------------------------------------------------
__global__ void permute_w(const float* __restrict__ Wih, const float* __restrict__ Whh,
                          const float* __restrict__ bih, const float* __restrict__ bhh,
                          float* __restrict__ Wih_p, float* __restrict__ Whh_p,
                          float* __restrict__ bias_p)
{
    int g = blockIdx.x;            // 0..2047
    int q = g >> 9, j = g & 511;
    int gnew = j * 4 + q;
    const float4* s1 = (const float4*)&Wih[(size_t)g * CE];
    float4*       d1 = (float4*)&Wih_p[(size_t)gnew * CE];
    const float4* s2 = (const float4*)&Whh[(size_t)g * CH];
    float4*       d2 = (float4*)&Whh_p[(size_t)gnew * CH];
    d1[threadIdx.x] = s1[threadIdx.x];   // 128 thr * float4 = 512 floats
    d2[threadIdx.x] = s2[threadIdx.x];
    if (threadIdx.x == 0) bias_p[gnew] = bih[g] + bhh[g];
}

// ---------------------------------------------------------------------------
// seq[b, 1+t, :] = emb[seqs[b,t], :]
// ---------------------------------------------------------------------------
__global__ void gather_emb(const int* __restrict__ seqs, const float* __restrict__ emb,
                           float* __restrict__ seq)
{
    int t = blockIdx.x;            // 0..38
    int b = blockIdx.y;            // 0..127
    int tok = seqs[b * (CT - 1) + t];
    const float4* src = (const float4*)&emb[(size_t)tok * CE];
    float4*       dst = (float4*)&seq[((size_t)b * CT + 1 + t) * CE];
    dst[threadIdx.x] = src[threadIdx.x];
}

// ---------------------------------------------------------------------------
// fp32 GEMM: C[M,N] = A[M,K] @ B[N,K]^T + bias      (BM=BN=128, BK=16)
// 256 threads, 8x8 per thread. M must be multiple of 128; N,K mult of 4.
// ---------------------------------------------------------------------------
__global__ __launch_bounds__(256)
void gemm_bt(const float* __restrict__ A, int lda,
             const float* __restrict__ B, int ldb,
             const float* __restrict__ bias,
             float* __restrict__ C, int ldc,
             int M, int N, int K)
{
    __shared__ float As[16][132];
    __shared__ float Bs[16][132];
    const int tid = threadIdx.x;
    const int tx = tid & 15;       // 0..15 -> cols
    const int ty = tid >> 4;       // 0..15 -> rows
    const int m0 = blockIdx.y * 128;
    const int n0 = blockIdx.x * 128;

    float acc[8][8];
#pragma unroll
    for (int r = 0; r < 8; ++r)
#pragma unroll
        for (int c = 0; c < 8; ++c) acc[r][c] = 0.f;

    for (int k0 = 0; k0 < K; k0 += 16) {
#pragma unroll
        for (int p = 0; p < 2; ++p) {          // A tile 128x16 = 512 float4
            int v = tid + p * 256;
            int m = v >> 2;
            int kq = (v & 3) << 2;
            float4 a = *(const float4*)&A[(size_t)(m0 + m) * lda + k0 + kq];
            As[kq + 0][m] = a.x; As[kq + 1][m] = a.y;
            As[kq + 2][m] = a.z; As[kq + 3][m] = a.w;
        }
#pragma unroll
        for (int p = 0; p < 2; ++p) {          // B tile 128x16 (N-guarded)
            int v = tid + p * 256;
            int n = v >> 2;
            int kq = (v & 3) << 2;
            float4 b = make_float4(0.f, 0.f, 0.f, 0.f);
            if (n0 + n < N)
                b = *(const float4*)&B[(size_t)(n0 + n) * ldb + k0 + kq];
            Bs[kq + 0][n] = b.x; Bs[kq + 1][n] = b.y;
            Bs[kq + 2][n] = b.z; Bs[kq + 3][n] = b.w;
        }
        __syncthreads();
#pragma unroll
        for (int kk = 0; kk < 16; ++kk) {
            float4 a0 = *(const float4*)&As[kk][ty * 8];
            float4 a1 = *(const float4*)&As[kk][ty * 8 + 4];
            float4 b0 = *(const float4*)&Bs[kk][tx * 4];
            float4 b1 = *(const float4*)&Bs[kk][64 + tx * 4];
            float av[8] = {a0.x, a0.y, a0.z, a0.w, a1.x, a1.y, a1.z, a1.w};
            float bv[8] = {b0.x, b0.y, b0.z, b0.w, b1.x, b1.y, b1.z, b1.w};
#pragma unroll
            for (int r = 0; r < 8; ++r)
#pragma unroll
                for (int c = 0; c < 8; ++c)
                    acc[r][c] += av[r] * bv[c];
        }
        __syncthreads();
    }

    const int c0 = n0 + tx * 4;
    const int c1 = n0 + 64 + tx * 4;
    float4 bias0 = make_float4(0, 0, 0, 0), bias1 = make_float4(0, 0, 0, 0);
    if (c0 + 3 < N) bias0 = *(const float4*)&bias[c0];
    if (c1 + 3 < N) bias1 = *(const float4*)&bias[c1];
#pragma unroll
    for (int r = 0; r < 8; ++r) {
        int row = m0 + ty * 8 + r;
        if (c0 + 3 < N) {
            float4 o = make_float4(acc[r][0] + bias0.x, acc[r][1] + bias0.y,
                                   acc[r][2] + bias0.z, acc[r][3] + bias0.w);
            *(float4*)&C[(size_t)row * ldc + c0] = o;
        }
        if (c1 + 3 < N) {
            float4 o = make_float4(acc[r][4] + bias1.x, acc[r][5] + bias1.y,
                                   acc[r][6] + bias1.z, acc[r][7] + bias1.w);
            *(float4*)&C[(size_t)row * ldc + c1] = o;
        }
    }
}

// ---------------------------------------------------------------------------
// persistent cooperative LSTM: 256 blocks x 256 threads, one grid sync/step.
// block (bc,nc): batch rows bc*16..+15, interleaved gate cols nc*64..+63
// (= hidden units nc*16..+15).  h double-buffered in global; c stays in LDS.
// xg already contains b_ih+b_hh (interleaved).
// ---------------------------------------------------------------------------
__global__ __launch_bounds__(256)
void lstm_kernel(const float* __restrict__ xg,     // [B,T,G] interleaved+bias
                 const float* __restrict__ Whh,    // [G,H] interleaved rows
                 float* __restrict__ hbuf,         // [2,B,H]
                 float* __restrict__ h_all)        // [B,T,H]
{
    cg::grid_group grid = cg::this_grid();
    __shared__ float Hs[16][CH + 8];     // 16 x 520
    __shared__ float Ws[64][72];
    __shared__ float gLDS[16][68];
    __shared__ float c_s[16][16];

    const int tid = threadIdx.x;
    const int bc = blockIdx.x >> 5;      // 0..7
    const int nc = blockIdx.x & 31;      // 0..31
    const int b0 = bc * 16;
    const int n0 = nc * 64;
    const int j0 = nc * 16;

    const int b_l = tid >> 4;            // 0..15  (elementwise mapping)
    const int j_l = tid & 15;            // 0..15

    // ---- t = 0: h=0, c=0 -> gates = xg ----
    {
        float4 gv = *(const float4*)&xg[((size_t)(b0 + b_l) * CT + 0) * CG + n0 + j_l * 4];
        float i = 1.f / (1.f + expf(-gv.x));
        float f = 1.f / (1.f + expf(-gv.y));
        float g = tanhf(gv.z);
        float o = 1.f / (1.f + expf(-gv.w));
        float c = i * g;                 // f * 0 + i*g
        float h = o * tanhf(c);
        c_s[b_l][j_l] = c;
        hbuf[(size_t)(b0 + b_l) * CH + j0 + j_l] = h;                   // buf 0
        h_all[((size_t)(b0 + b_l) * CT + 0) * CH + j0 + j_l] = h;
    }
    grid.sync();

    const int ty = tid >> 5;             // 0..7  -> 2 batch rows ty*2+{0,1}
    const int tx = tid & 31;             // 0..31 -> 2 cols tx*2+{0,1}

    for (int t = 1; t < CT; ++t) {
        const float* hprev = hbuf + (size_t)((t - 1) & 1) * CB * CH;
        // stage h rows [16][512]
#pragma unroll
        for (int p = 0; p < 8; ++p) {
            int v = tid + p * 256;
            int m = v >> 7;
            int kq = (v & 127) << 2;
            *(float4*)&Hs[m][kq] = *(const float4*)&hprev[(size_t)(b0 + m) * CH + kq];
        }
        // acc init from xg (bias already folded in)
        float acc[2][2];
#pragma unroll
        for (int r = 0; r < 2; ++r) {
            float2 x2 = *(const float2*)&xg[((size_t)(b0 + ty * 2 + r) * CT + t) * CG + n0 + tx * 2];
            acc[r][0] = x2.x; acc[r][1] = x2.y;
        }
        for (int kc = 0; kc < CH; kc += 64) {
#pragma unroll
            for (int p = 0; p < 4; ++p) {     // W tile 64x64
                int v = tid + p * 256;
                int nl = v >> 4;
                int kq = (v & 15) << 2;
                *(float4*)&Ws[nl][kq] = *(const float4*)&Whh[(size_t)(n0 + nl) * CH + kc + kq];
            }
            __syncthreads();
#pragma unroll
            for (int kk = 0; kk < 64; kk += 4) {
                float4 h0 = *(const float4*)&Hs[ty * 2 + 0][kc + kk];
                float4 h1 = *(const float4*)&Hs[ty * 2 + 1][kc + kk];
                float4 w0 = *(const float4*)&Ws[tx * 2 + 0][kk];
                float4 w1 = *(const float4*)&Ws[tx * 2 + 1][kk];
                acc[0][0] += h0.x * w0.x + h0.y * w0.y + h0.z * w0.z + h0.w * w0.w;
                acc[0][1] += h0.x * w1.x + h0.y * w1.y + h0.z * w1.z + h0.w * w1.w;
                acc[1][0] += h1.x * w0.x + h1.y * w0.y + h1.z * w0.z + h1.w * w0.w;
                acc[1][1] += h1.x * w1.x + h1.y * w1.y + h1.z * w1.z + h1.w * w1.w;
            }
            __syncthreads();
        }
        // gates -> LDS, then fused elementwise
#pragma unroll
        for (int r = 0; r < 2; ++r) {
            gLDS[ty * 2 + r][tx * 2 + 0] = acc[r][0];
            gLDS[ty * 2 + r][tx * 2 + 1] = acc[r][1];
        }
        __syncthreads();
        {
            float4 gv = *(const float4*)&gLDS[b_l][j_l * 4];
            float i = 1.f / (1.f + expf(-gv.x));
            float f = 1.f / (1.f + expf(-gv.y));
            float g = tanhf(gv.z);
            float o = 1.f / (1.f + expf(-gv.w));
            float c = f * c_s[b_l][j_l] + i * g;
            float h = o * tanhf(c);
            c_s[b_l][j_l] = c;
            hbuf[(size_t)(t & 1) * CB * CH + (size_t)(b0 + b_l) * CH + j0 + j_l] = h;
            h_all[((size_t)(b0 + b_l) * CT + t) * CH + j0 + j_l] = h;
        }
        grid.sync();
    }
}

// ---------------------------------------------------------------------------
extern "C" void kernel_launch(void* const* d_in, const int* in_sizes, int n_in,
                              void* d_out, int out_size, void* d_ws, size_t ws_size,
                              hipStream_t stream)
{
    const float* features = (const float*)d_in[0];
    const int*   seqs     = (const int*)d_in[1];
    // d_in[2] = lengths (unused by forward)
    const float* W_in  = (const float*)d_in[3];
    const float* b_in  = (const float*)d_in[4];
    const float* emb   = (const float*)d_in[5];
    const float* W_ih  = (const float*)d_in[6];
    const float* W_hh  = (const float*)d_in[7];
    const float* b_ih  = (const float*)d_in[8];
    const float* b_hh  = (const float*)d_in[9];
    const float* W_out = (const float*)d_in[10];
    const float* b_out = (const float*)d_in[11];
    float* out = (float*)d_out;

    float* ws = (float*)d_ws;
    float* Wih_p  = ws;  ws += (size_t)CG * CE;      // 1M floats
    float* Whh_p  = ws;  ws += (size_t)CG * CH;      // 1M
    float* bias_p = ws;  ws += CG;                   // 2K
    float* seq    = ws;  ws += (size_t)CB * CT * CE; // 2.6M
    float* xg     = ws;  ws += (size_t)CB * CT * CG; // 10.5M
    float* h_all  = ws;  ws += (size_t)CB * CT * CH; // 2.6M
    float* hbuf   = ws;  ws += (size_t)2 * CB * CH;  // 128K   (total ~72 MB)

    // 1) interleave gate weights, fold biases
    permute_w<<<CG, 128, 0, stream>>>(W_ih, W_hh, b_ih, b_hh, Wih_p, Whh_p, bias_p);
    // 2) seq[:,1:,:] = emb[seqs]
    gather_emb<<<dim3(CT - 1, CB), 128, 0, stream>>>(seqs, emb, seq);
    // 3) seq[:,0,:] = features @ W_in^T + b_in   (C rows strided by T*E)
    gemm_bt<<<dim3(CE / 128, CB / 128), 256, 0, stream>>>(
        features, CF, W_in, CF, b_in, seq, CT * CE, CB, CE, CF);
    // 4) xg = seq2d @ Wih_p^T + (b_ih+b_hh)   [5120 x 2048]
    gemm_bt<<<dim3(CG / 128, (CB * CT) / 128), 256, 0, stream>>>(
        seq, CE, Wih_p, CE, bias_p, xg, CG, CB * CT, CG, CE);
    // 5) 40-step LSTM scan (cooperative, 1 grid sync per step)
    {
        void* args[] = {(void*)&xg, (void*)&Whh_p, (void*)&hbuf, (void*)&h_all};
        hipLaunchCooperativeKernel((void*)lstm_kernel, dim3(256), dim3(256),
                                   args, 0, stream);
    }
    // 6) logits = h_all @ W_out^T + b_out   [5120 x 10000]
    gemm_bt<<<dim3((CV + 127) / 128, (CB * CT) / 128), 256, 0, stream>>>(
        h_all, CH, W_out, CH, b_out, out, CV, CB * CT, CV, CH);
}

// Round 3
// 1747.248 us; speedup vs baseline: 1.7898x; 1.7898x over previous
//
#include <hip/hip_runtime.h>
#include <hip/hip_cooperative_groups.h>

namespace cg = cooperative_groups;

#define CB 128     // batch
#define CF 1536    // feature
#define CE 512     // embed
#define CH 512     // hidden
#define CG 2048    // 4*H (q-major: gate q = rows q*512..q*512+511)
#define CV 10000   // vocab
#define CVP 10112  // vocab padded to 79*128
#define CT 40      // max len

typedef unsigned short u16;
typedef __attribute__((ext_vector_type(8))) short bf16x8;
typedef __attribute__((ext_vector_type(4))) float f32x4;

#define MFMA16(a, b, c) __builtin_amdgcn_mfma_f32_16x16x32_bf16(a, b, c, 0, 0, 0)

__device__ __forceinline__ u16 f2bf(float x) {
    unsigned u = __float_as_uint(x);
    u += 0x7FFFu + ((u >> 16) & 1u);          // RNE (finite values only here)
    return (u16)(u >> 16);
}

__device__ __forceinline__ void gload_lds16(const void* g, void* l) {
    __builtin_amdgcn_global_load_lds(
        (const __attribute__((address_space(1))) unsigned int*)g,
        (__attribute__((address_space(3))) unsigned int*)l, 16, 0, 0);
}

__device__ __forceinline__ float sigm(float x) { return 1.f / (1.f + expf(-x)); }

// ---------------------------------------------------------------------------
// fp32 -> bf16 conversion (vectorized, grid-stride over float4 chunks)
// ---------------------------------------------------------------------------
__global__ void cvt_bf16(const float* __restrict__ s, u16* __restrict__ d, int n4) {
    int i = blockIdx.x * blockDim.x + threadIdx.x;
    for (; i < n4; i += gridDim.x * blockDim.x) {
        float4 v = ((const float4*)s)[i];
        ushort4 o = make_ushort4(f2bf(v.x), f2bf(v.y), f2bf(v.z), f2bf(v.w));
        ((ushort4*)d)[i] = o;
    }
}

// W_out [CV][CE] fp32 -> [CVP][CE] bf16, zero-padded rows
__global__ void cvt_wout(const float* __restrict__ s, u16* __restrict__ d) {
    const int n4 = CVP * CE / 4;
    int i = blockIdx.x * blockDim.x + threadIdx.x;
    for (; i < n4; i += gridDim.x * blockDim.x) {
        int e = i * 4;
        int row = e >> 9;           // /512
        int col = e & 511;
        ushort4 o;
        if (row < CV) {
            float4 v = *(const float4*)(s + (size_t)row * CE + col);
            o = make_ushort4(f2bf(v.x), f2bf(v.y), f2bf(v.z), f2bf(v.w));
        } else {
            o = make_ushort4(0, 0, 0, 0);
        }
        ((ushort4*)d)[i] = o;
    }
}

__global__ void bias_sum(const float* __restrict__ a, const float* __restrict__ b,
                         float* __restrict__ o) {
    int i = blockIdx.x * blockDim.x + threadIdx.x;
    if (i < CG) o[i] = a[i] + b[i];
}

// ---------------------------------------------------------------------------
// seq[b, 1+t, :] = bf16(emb[seqs[b,t], :])
// ---------------------------------------------------------------------------
__global__ void gather_emb(const int* __restrict__ seqs, const float* __restrict__ emb,
                           u16* __restrict__ seq) {
    int t = blockIdx.x;            // 0..38
    int b = blockIdx.y;            // 0..127
    int tok = seqs[b * (CT - 1) + t];
    float4 v = ((const float4*)(emb + (size_t)tok * CE))[threadIdx.x];
    ushort4 o = make_ushort4(f2bf(v.x), f2bf(v.y), f2bf(v.z), f2bf(v.w));
    *(ushort4*)(seq + ((size_t)b * CT + 1 + t) * CE + threadIdx.x * 4) = o;
}

// ---------------------------------------------------------------------------
// x0 = features @ W_in^T + b_in -> bf16 into seq[:,0,:]
// grid (8 n-tiles of 64, 8 m-tiles of 16), 4 waves: wave w = n-frag w.
// Fragments read straight from global (L2-resident, small kernel).
// ---------------------------------------------------------------------------
__global__ __launch_bounds__(256)
void x0_kernel(const u16* __restrict__ fea, const u16* __restrict__ win,
               const float* __restrict__ b_in, u16* __restrict__ seq) {
    const int tid = threadIdx.x, lane = tid & 63, w = tid >> 6;
    const int m0 = blockIdx.y * 16, n0 = blockIdx.x * 64;
    const int r16 = lane & 15, koff = lane >> 4;
    const u16* ap = fea + (size_t)(m0 + r16) * CF + koff * 8;
    const u16* bp = win + (size_t)(n0 + w * 16 + r16) * CF + koff * 8;
    f32x4 acc0 = {0.f, 0.f, 0.f, 0.f}, acc1 = {0.f, 0.f, 0.f, 0.f};
#pragma unroll
    for (int ks = 0; ks < 48; ++ks) {
        bf16x8 af = *(const bf16x8*)(ap + ks * 32);
        bf16x8 bf = *(const bf16x8*)(bp + ks * 32);
        if (ks & 1) acc1 = MFMA16(af, bf, acc1);
        else        acc0 = MFMA16(af, bf, acc0);
    }
    const int col = n0 + w * 16 + r16;
    const float bb = b_in[col];
#pragma unroll
    for (int r = 0; r < 4; ++r) {
        int brow = m0 + koff * 4 + r;
        seq[(size_t)brow * (CT * CE) + col] = f2bf(acc0[r] + acc1[r] + bb);
    }
}

// ---------------------------------------------------------------------------
// bf16 MFMA GEMM: C[M,N] = A[M,K] @ B[N,K]^T + bias (fp32 out)
// 128x128 tile, BK=32, 4 waves 2x2 (64x64/wave, 4x4 frags of 16x16x32).
// global_load_lds(16B) staging with slot-swizzle (phys = slot ^ ((row>>1)&3)).
// M,N multiples of 128; stores/bias guarded by Nvalid.
// ---------------------------------------------------------------------------
__global__ __launch_bounds__(256)
void gemm_bf16(const u16* __restrict__ A, int lda, const u16* __restrict__ B, int ldb,
               const float* __restrict__ bias, float* __restrict__ C, int ldc,
               int K, int Nvalid) {
    __shared__ __align__(16) u16 As[4096];   // [128 rows][32 k] bf16, 64B rows
    __shared__ __align__(16) u16 Bs[4096];
    const int tid = threadIdx.x, lane = tid & 63;
    const int wid = tid >> 6, wm = wid >> 1, wn = wid & 1;
    const int m0 = blockIdx.y * 128, n0 = blockIdx.x * 128;
    const int r16 = lane & 15, koff = lane >> 4;

    f32x4 acc[4][4];
#pragma unroll
    for (int i = 0; i < 4; ++i)
#pragma unroll
        for (int j = 0; j < 4; ++j) acc[i][j] = (f32x4){0.f, 0.f, 0.f, 0.f};

    for (int k0 = 0; k0 < K; k0 += 32) {
#pragma unroll
        for (int c = 0; c < 2; ++c) {
            int flat = c * 4096 + tid * 16;          // byte offset in tile
            int row = flat >> 6;
            int phys = (flat >> 4) & 3;
            int logi = phys ^ ((row >> 1) & 3);
            gload_lds16(A + (size_t)(m0 + row) * lda + k0 + logi * 8, (char*)As + flat);
            gload_lds16(B + (size_t)(n0 + row) * ldb + k0 + logi * 8, (char*)Bs + flat);
        }
        __syncthreads();
        bf16x8 a[4], b[4];
#pragma unroll
        for (int i = 0; i < 4; ++i) {
            int row = wm * 64 + i * 16 + r16;
            int phys = koff ^ ((row >> 1) & 3);
            a[i] = *(const bf16x8*)((const char*)As + row * 64 + phys * 16);
        }
#pragma unroll
        for (int j = 0; j < 4; ++j) {
            int row = wn * 64 + j * 16 + r16;
            int phys = koff ^ ((row >> 1) & 3);
            b[j] = *(const bf16x8*)((const char*)Bs + row * 64 + phys * 16);
        }
#pragma unroll
        for (int i = 0; i < 4; ++i)
#pragma unroll
            for (int j = 0; j < 4; ++j) acc[i][j] = MFMA16(a[i], b[j], acc[i][j]);
        __syncthreads();
    }

#pragma unroll
    for (int j = 0; j < 4; ++j) {
        int col = n0 + wn * 64 + j * 16 + r16;
        bool ok = col < Nvalid;
        float bj = ok ? bias[col] : 0.f;
#pragma unroll
        for (int i = 0; i < 4; ++i) {
            int rowb = m0 + wm * 64 + i * 16 + koff * 4;
#pragma unroll
            for (int r = 0; r < 4; ++r)
                if (ok) C[(size_t)(rowb + r) * ldc + col] = acc[i][j][r] + bj;
        }
    }
}

// ---------------------------------------------------------------------------
// Cooperative LSTM scan. 256 blocks x 256 threads (4 waves).
// Block (bc,nc): batch rows bc*16..+15, hidden units nc*16..+15.
// Wave q computes gate q's 16x16 fragment; W_hh frags live in registers.
// h staged per step via global_load_lds into swizzled LDS; c in VGPRs.
// ---------------------------------------------------------------------------
__global__ __launch_bounds__(256)
void lstm_kernel(const float* __restrict__ xg,   // [B,T,G] fp32, q-major, bias folded
                 const u16* __restrict__ Whh,    // [G,H] bf16
                 u16* __restrict__ hbuf,         // [2,B,H] bf16
                 u16* __restrict__ hall)         // [B,T,H] bf16
{
    cg::grid_group grid = cg::this_grid();
    __shared__ __align__(16) u16 Hs[16 * 512];   // 16 rows x 1KB, slot-swizzled
    __shared__ float gS[4][16][17];

    const int tid = threadIdx.x, lane = tid & 63, q = tid >> 6;
    const int bc = blockIdx.x >> 5, nc = blockIdx.x & 31;
    const int b0 = bc * 16, j0 = nc * 16;
    const int r16 = lane & 15, koff = lane >> 4;
    const int b_l = tid >> 4, j_l = tid & 15;

    // W_hh fragments for this wave's gate rows, resident in registers.
    bf16x8 wf[16];
    {
        const u16* wrow = Whh + (size_t)(q * CH + j0 + r16) * CH + koff * 8;
#pragma unroll
        for (int ks = 0; ks < 16; ++ks) wf[ks] = *(const bf16x8*)(wrow + ks * 32);
    }

    float c_state;
    // ---- t = 0: gates = xg (h=0, c=0) ----
    {
        const float* xp = xg + ((size_t)(b0 + b_l) * CT + 0) * CG + j0 + j_l;
        float gi = xp[0 * CH], gf = xp[1 * CH], gg = xp[2 * CH], go = xp[3 * CH];
        float iv = sigm(gi), gv = tanhf(gg), ov = sigm(go);
        (void)gf;
        c_state = iv * gv;               // f * c0 + i*g with c0 = 0
        float h = ov * tanhf(c_state);
        u16 hb = f2bf(h);
        hbuf[(size_t)(b0 + b_l) * CH + j0 + j_l] = hb;
        hall[((size_t)(b0 + b_l) * CT + 0) * CH + j0 + j_l] = hb;
    }
    grid.sync();

    for (int t = 1; t < CT; ++t) {
        const u16* hprev = hbuf + (size_t)((t - 1) & 1) * CB * CH;
        // stage h rows b0..b0+15 (16KB bf16), pre-swizzled source
#pragma unroll
        for (int c = 0; c < 4; ++c) {
            int flat = c * 4096 + tid * 16;     // byte
            int row = flat >> 10;
            int phys = (flat >> 4) & 63;
            int logi = phys ^ (row & 7);
            gload_lds16(hprev + (size_t)(b0 + row) * CH + logi * 8, (char*)Hs + flat);
        }
        // xg preload for this fragment (4 rows)
        float xv[4];
#pragma unroll
        for (int r = 0; r < 4; ++r)
            xv[r] = xg[((size_t)(b0 + koff * 4 + r) * CT + t) * CG + q * CH + j0 + r16];
        __syncthreads();

        f32x4 acc0 = {0.f, 0.f, 0.f, 0.f}, acc1 = {0.f, 0.f, 0.f, 0.f};
#pragma unroll
        for (int ks = 0; ks < 16; ++ks) {
            int slot = ks * 4 + koff;
            int phys = slot ^ (r16 & 7);
            bf16x8 af = *(const bf16x8*)((const char*)Hs + r16 * 1024 + phys * 16);
            if (ks & 1) acc1 = MFMA16(af, wf[ks], acc1);
            else        acc0 = MFMA16(af, wf[ks], acc0);
        }
#pragma unroll
        for (int r = 0; r < 4; ++r)
            gS[q][koff * 4 + r][r16] = acc0[r] + acc1[r] + xv[r];
        __syncthreads();

        {
            float gi = gS[0][b_l][j_l], gf = gS[1][b_l][j_l];
            float gg = gS[2][b_l][j_l], go = gS[3][b_l][j_l];
            float iv = sigm(gi), fv = sigm(gf), gv = tanhf(gg), ov = sigm(go);
            c_state = fv * c_state + iv * gv;
            float h = ov * tanhf(c_state);
            u16 hb = f2bf(h);
            hbuf[(size_t)(t & 1) * CB * CH + (size_t)(b0 + b_l) * CH + j0 + j_l] = hb;
            hall[((size_t)(b0 + b_l) * CT + t) * CH + j0 + j_l] = hb;
        }
        grid.sync();
    }
}

// ---------------------------------------------------------------------------
extern "C" void kernel_launch(void* const* d_in, const int* in_sizes, int n_in,
                              void* d_out, int out_size, void* d_ws, size_t ws_size,
                              hipStream_t stream) {
    const float* features = (const float*)d_in[0];
    const int*   seqs     = (const int*)d_in[1];
    const float* W_in  = (const float*)d_in[3];
    const float* b_in  = (const float*)d_in[4];
    const float* emb   = (const float*)d_in[5];
    const float* W_ih  = (const float*)d_in[6];
    const float* W_hh  = (const float*)d_in[7];
    const float* b_ih  = (const float*)d_in[8];
    const float* b_hh  = (const float*)d_in[9];
    const float* W_out = (const float*)d_in[10];
    const float* b_out = (const float*)d_in[11];
    float* out = (float*)d_out;

    char* p = (char*)d_ws;
    float* xg    = (float*)p;  p += (size_t)CB * CT * CG * 4;   // 41.9 MB
    u16* seqb    = (u16*)p;    p += (size_t)CB * CT * CE * 2;   // 5.2 MB
    u16* hallb   = (u16*)p;    p += (size_t)CB * CT * CH * 2;   // 5.2 MB
    u16* hbufb   = (u16*)p;    p += (size_t)2 * CB * CH * 2;    // 256 KB
    u16* feab    = (u16*)p;    p += (size_t)CB * CF * 2;
    u16* winb    = (u16*)p;    p += (size_t)CE * CF * 2;
    u16* wihb    = (u16*)p;    p += (size_t)CG * CE * 2;
    u16* whhb    = (u16*)p;    p += (size_t)CG * CH * 2;
    u16* woutb   = (u16*)p;    p += (size_t)CVP * CE * 2;
    float* biasp = (float*)p;  p += (size_t)CG * 4;

    // --- prep: conversions ---
    cvt_bf16<<<192, 256, 0, stream>>>(features, feab, CB * CF / 4);
    cvt_bf16<<<768, 256, 0, stream>>>(W_in, winb, CE * CF / 4);
    cvt_bf16<<<1024, 256, 0, stream>>>(W_ih, wihb, CG * CE / 4);
    cvt_bf16<<<1024, 256, 0, stream>>>(W_hh, whhb, CG * CH / 4);
    cvt_wout<<<2048, 256, 0, stream>>>(W_out, woutb);
    bias_sum<<<8, 256, 0, stream>>>(b_ih, b_hh, biasp);

    // --- seq assembly ---
    gather_emb<<<dim3(CT - 1, CB), 128, 0, stream>>>(seqs, emb, seqb);
    x0_kernel<<<dim3(8, 8), 256, 0, stream>>>(feab, winb, b_in, seqb);

    // --- xg = seq @ W_ih^T + (b_ih+b_hh)  [5120 x 2048], fp32 out ---
    gemm_bf16<<<dim3(CG / 128, CB * CT / 128), 256, 0, stream>>>(
        seqb, CE, wihb, CE, biasp, xg, CG, CE, CG);

    // --- LSTM scan (cooperative) ---
    {
        const float* xg_c = xg;  const u16* whh_c = whhb;
        u16* hb_c = hbufb;       u16* ha_c = hallb;
        void* args[] = {(void*)&xg_c, (void*)&whh_c, (void*)&hb_c, (void*)&ha_c};
        hipLaunchCooperativeKernel((void*)lstm_kernel, dim3(256), dim3(256),
                                   args, 0, stream);
    }

    // --- logits = h_all @ W_out^T + b_out  [5120 x 10000] ---
    gemm_bf16<<<dim3(CVP / 128, CB * CT / 128), 256, 0, stream>>>(
        hallb, CH, woutb, CH, b_out, out, CV, CH, CV);
}

// Round 4
// 694.592 us; speedup vs baseline: 4.5023x; 2.5155x over previous
//
#include <hip/hip_runtime.h>
#include <hip/hip_cooperative_groups.h>

#define CB 128     // batch
#define CF 1536    // feature
#define CE 512     // embed
#define CH 512     // hidden
#define CG 2048    // 4*H (q-major: gate q = rows q*512..q*512+511)
#define CV 10000   // vocab
#define CVP 10112  // vocab padded to 79*128
#define CT 40      // max len

typedef unsigned short u16;
typedef __attribute__((ext_vector_type(8))) short bf16x8;
typedef __attribute__((ext_vector_type(4))) float f32x4;

#define MFMA16(a, b, c) __builtin_amdgcn_mfma_f32_16x16x32_bf16(a, b, c, 0, 0, 0)

__device__ __forceinline__ u16 f2bf(float x) {
    unsigned u = __float_as_uint(x);
    u += 0x7FFFu + ((u >> 16) & 1u);          // RNE (finite values only here)
    return (u16)(u >> 16);
}

__device__ __forceinline__ void gload_lds16(const void* g, void* l) {
    __builtin_amdgcn_global_load_lds(
        (const __attribute__((address_space(1))) unsigned int*)g,
        (__attribute__((address_space(3))) unsigned int*)l, 16, 0, 0);
}

__device__ __forceinline__ float sigm(float x) { return 1.f / (1.f + expf(-x)); }

// ---------------------------------------------------------------------------
// fp32 -> bf16 conversion (vectorized, grid-stride over float4 chunks)
// ---------------------------------------------------------------------------
__global__ void cvt_bf16(const float* __restrict__ s, u16* __restrict__ d, int n4) {
    int i = blockIdx.x * blockDim.x + threadIdx.x;
    for (; i < n4; i += gridDim.x * blockDim.x) {
        float4 v = ((const float4*)s)[i];
        ushort4 o = make_ushort4(f2bf(v.x), f2bf(v.y), f2bf(v.z), f2bf(v.w));
        ((ushort4*)d)[i] = o;
    }
}

// W_out [CV][CE] fp32 -> [CVP][CE] bf16, zero-padded rows
__global__ void cvt_wout(const float* __restrict__ s, u16* __restrict__ d) {
    const int n4 = CVP * CE / 4;
    int i = blockIdx.x * blockDim.x + threadIdx.x;
    for (; i < n4; i += gridDim.x * blockDim.x) {
        int e = i * 4;
        int row = e >> 9;           // /512
        int col = e & 511;
        ushort4 o;
        if (row < CV) {
            float4 v = *(const float4*)(s + (size_t)row * CE + col);
            o = make_ushort4(f2bf(v.x), f2bf(v.y), f2bf(v.z), f2bf(v.w));
        } else {
            o = make_ushort4(0, 0, 0, 0);
        }
        ((ushort4*)d)[i] = o;
    }
}

__global__ void bias_sum(const float* __restrict__ a, const float* __restrict__ b,
                         float* __restrict__ o) {
    int i = blockIdx.x * blockDim.x + threadIdx.x;
    if (i < CG) o[i] = a[i] + b[i];
}

__global__ void zero_cnt(unsigned* __restrict__ cnt) {
    if (threadIdx.x < 128) cnt[threadIdx.x] = 0;
}

// ---------------------------------------------------------------------------
// seq[b, 1+t, :] = bf16(emb[seqs[b,t], :])
// ---------------------------------------------------------------------------
__global__ void gather_emb(const int* __restrict__ seqs, const float* __restrict__ emb,
                           u16* __restrict__ seq) {
    int t = blockIdx.x;            // 0..38
    int b = blockIdx.y;            // 0..127
    int tok = seqs[b * (CT - 1) + t];
    float4 v = ((const float4*)(emb + (size_t)tok * CE))[threadIdx.x];
    ushort4 o = make_ushort4(f2bf(v.x), f2bf(v.y), f2bf(v.z), f2bf(v.w));
    *(ushort4*)(seq + ((size_t)b * CT + 1 + t) * CE + threadIdx.x * 4) = o;
}

// ---------------------------------------------------------------------------
// x0 = features @ W_in^T + b_in -> bf16 into seq[:,0,:]
// ---------------------------------------------------------------------------
__global__ __launch_bounds__(256)
void x0_kernel(const u16* __restrict__ fea, const u16* __restrict__ win,
               const float* __restrict__ b_in, u16* __restrict__ seq) {
    const int tid = threadIdx.x, lane = tid & 63, w = tid >> 6;
    const int m0 = blockIdx.y * 16, n0 = blockIdx.x * 64;
    const int r16 = lane & 15, koff = lane >> 4;
    const u16* ap = fea + (size_t)(m0 + r16) * CF + koff * 8;
    const u16* bp = win + (size_t)(n0 + w * 16 + r16) * CF + koff * 8;
    f32x4 acc0 = {0.f, 0.f, 0.f, 0.f}, acc1 = {0.f, 0.f, 0.f, 0.f};
#pragma unroll
    for (int ks = 0; ks < 48; ++ks) {
        bf16x8 af = *(const bf16x8*)(ap + ks * 32);
        bf16x8 bf = *(const bf16x8*)(bp + ks * 32);
        if (ks & 1) acc1 = MFMA16(af, bf, acc1);
        else        acc0 = MFMA16(af, bf, acc0);
    }
    const int col = n0 + w * 16 + r16;
    const float bb = b_in[col];
#pragma unroll
    for (int r = 0; r < 4; ++r) {
        int brow = m0 + koff * 4 + r;
        seq[(size_t)brow * (CT * CE) + col] = f2bf(acc0[r] + acc1[r] + bb);
    }
}

// ---------------------------------------------------------------------------
// bf16 MFMA GEMM: C[M,N] = A[M,K] @ B[N,K]^T + bias (fp32 out)
// 128x128 tile, BK=32, 4 waves 2x2 (64x64/wave, 4x4 frags of 16x16x32).
// ---------------------------------------------------------------------------
__global__ __launch_bounds__(256)
void gemm_bf16(const u16* __restrict__ A, int lda, const u16* __restrict__ B, int ldb,
               const float* __restrict__ bias, float* __restrict__ C, int ldc,
               int K, int Nvalid) {
    __shared__ __align__(16) u16 As[4096];   // [128 rows][32 k] bf16, 64B rows
    __shared__ __align__(16) u16 Bs[4096];
    const int tid = threadIdx.x, lane = tid & 63;
    const int wid = tid >> 6, wm = wid >> 1, wn = wid & 1;
    const int m0 = blockIdx.y * 128, n0 = blockIdx.x * 128;
    const int r16 = lane & 15, koff = lane >> 4;

    f32x4 acc[4][4];
#pragma unroll
    for (int i = 0; i < 4; ++i)
#pragma unroll
        for (int j = 0; j < 4; ++j) acc[i][j] = (f32x4){0.f, 0.f, 0.f, 0.f};

    for (int k0 = 0; k0 < K; k0 += 32) {
#pragma unroll
        for (int c = 0; c < 2; ++c) {
            int flat = c * 4096 + tid * 16;          // byte offset in tile
            int row = flat >> 6;
            int phys = (flat >> 4) & 3;
            int logi = phys ^ ((row >> 1) & 3);
            gload_lds16(A + (size_t)(m0 + row) * lda + k0 + logi * 8, (char*)As + flat);
            gload_lds16(B + (size_t)(n0 + row) * ldb + k0 + logi * 8, (char*)Bs + flat);
        }
        __syncthreads();
        bf16x8 a[4], b[4];
#pragma unroll
        for (int i = 0; i < 4; ++i) {
            int row = wm * 64 + i * 16 + r16;
            int phys = koff ^ ((row >> 1) & 3);
            a[i] = *(const bf16x8*)((const char*)As + row * 64 + phys * 16);
        }
#pragma unroll
        for (int j = 0; j < 4; ++j) {
            int row = wn * 64 + j * 16 + r16;
            int phys = koff ^ ((row >> 1) & 3);
            b[j] = *(const bf16x8*)((const char*)Bs + row * 64 + phys * 16);
        }
#pragma unroll
        for (int i = 0; i < 4; ++i)
#pragma unroll
            for (int j = 0; j < 4; ++j) acc[i][j] = MFMA16(a[i], b[j], acc[i][j]);
        __syncthreads();
    }

#pragma unroll
    for (int j = 0; j < 4; ++j) {
        int col = n0 + wn * 64 + j * 16 + r16;
        bool ok = col < Nvalid;
        float bj = ok ? bias[col] : 0.f;
#pragma unroll
        for (int i = 0; i < 4; ++i) {
            int rowb = m0 + wm * 64 + i * 16 + koff * 4;
#pragma unroll
            for (int r = 0; r < 4; ++r)
                if (ok) C[(size_t)(rowb + r) * ldc + col] = acc[i][j][r] + bj;
        }
    }
}

// ---------------------------------------------------------------------------
// Persistent LSTM scan: 32 blocks = 4 batch-groups (32 rows) x 8 unit-blocks
// (64 units). 512 threads (8 waves). W_hh slice [256 g-rows x 512] in regs.
// Cross-block sync: per-group 8-block counter barrier (device-scope atomics),
// one barrier per step; hbuf double-buffered.
// Wave w: gate q = w>>1, unit sub-block jsub = (w&1)*32; output [32b x 32u].
// ---------------------------------------------------------------------------
__global__ __launch_bounds__(512)
void lstm_kernel(const float* __restrict__ xg,   // [B,T,G] fp32, q-major, bias folded
                 const u16* __restrict__ Whh,    // [G,H] bf16, q-major rows
                 u16* __restrict__ hbuf,         // [2,B,H] bf16
                 u16* __restrict__ hall,         // [B,T,H] bf16
                 unsigned* __restrict__ cnt)     // [4] padded x32, zeroed
{
    __shared__ __align__(16) u16 Hs[32 * 512];   // 32 rows x 1KB, slot-swizzled
    __shared__ float gS[4][32][68];

    const int tid = threadIdx.x, lane = tid & 63, w = tid >> 6;
    const int bc = blockIdx.x >> 3, nc = blockIdx.x & 7;
    const int b0 = bc * 32, j0 = nc * 64;
    const int q = w >> 1, jsub = (w & 1) * 32;
    const int r16 = lane & 15, koff = lane >> 4;
    const int j_l = tid & 63;            // elementwise: unit within slice
    const int bq = tid >> 6;             // elementwise: rows bq*4..+3

    // W_hh fragments resident in registers: wf[n-tile][k-step], 128 VGPRs
    bf16x8 wf[2][16];
#pragma unroll
    for (int n = 0; n < 2; ++n) {
        const u16* wrow = Whh + (size_t)(q * CH + j0 + jsub + n * 16 + r16) * CH + koff * 8;
#pragma unroll
        for (int ks = 0; ks < 16; ++ks) wf[n][ks] = *(const bf16x8*)(wrow + ks * 32);
    }

    float c_st[4] = {0.f, 0.f, 0.f, 0.f};
    unsigned target = 0;

    for (int t = 0; t < CT; ++t) {
        // prefetch xg for the fused elementwise (coalesced 256B per wave-row)
        float xq[4][4];
#pragma unroll
        for (int qq = 0; qq < 4; ++qq)
#pragma unroll
            for (int r = 0; r < 4; ++r)
                xq[qq][r] = xg[((size_t)(b0 + bq * 4 + r) * CT + t) * CG + qq * CH + j0 + j_l];

        if (t > 0) {
            const u16* hprev = hbuf + (size_t)((t - 1) & 1) * CB * CH;
            // stage h [32][512] bf16, swizzled source -> linear LDS
#pragma unroll
            for (int c = 0; c < 4; ++c) {
                int flat = c * 8192 + tid * 16;     // byte
                int row = flat >> 10;               // 0..31 (wave-uniform)
                int phys = (flat >> 4) & 63;        // = lane
                int logi = phys ^ (row & 7);
                gload_lds16(hprev + (size_t)(b0 + row) * CH + logi * 8, (char*)Hs + flat);
            }
            __syncthreads();

            f32x4 acc[2][2];
#pragma unroll
            for (int i = 0; i < 2; ++i)
#pragma unroll
                for (int j = 0; j < 2; ++j) acc[i][j] = (f32x4){0.f, 0.f, 0.f, 0.f};
#pragma unroll
            for (int ks = 0; ks < 16; ++ks) {
                int row0 = r16, row1 = 16 + r16;
                int ph0 = (ks * 4 + koff) ^ (row0 & 7);
                int ph1 = (ks * 4 + koff) ^ (row1 & 7);
                bf16x8 a0 = *(const bf16x8*)((const char*)Hs + row0 * 1024 + ph0 * 16);
                bf16x8 a1 = *(const bf16x8*)((const char*)Hs + row1 * 1024 + ph1 * 16);
                acc[0][0] = MFMA16(a0, wf[0][ks], acc[0][0]);
                acc[0][1] = MFMA16(a0, wf[1][ks], acc[0][1]);
                acc[1][0] = MFMA16(a1, wf[0][ks], acc[1][0]);
                acc[1][1] = MFMA16(a1, wf[1][ks], acc[1][1]);
            }
            // exchange gate sums via LDS
#pragma unroll
            for (int mi = 0; mi < 2; ++mi)
#pragma unroll
                for (int ni = 0; ni < 2; ++ni)
#pragma unroll
                    for (int r = 0; r < 4; ++r)
                        gS[q][mi * 16 + koff * 4 + r][jsub + ni * 16 + r16] = acc[mi][ni][r];
            __syncthreads();
        }

        // fused elementwise: 4 batch rows per thread, unit j_l
#pragma unroll
        for (int r = 0; r < 4; ++r) {
            int b = bq * 4 + r;
            float gi = xq[0][r], gf = xq[1][r], gg = xq[2][r], go = xq[3][r];
            if (t > 0) {
                gi += gS[0][b][j_l]; gf += gS[1][b][j_l];
                gg += gS[2][b][j_l]; go += gS[3][b][j_l];
            }
            float iv = sigm(gi), fv = sigm(gf), gv = tanhf(gg), ov = sigm(go);
            float c = (t > 0 ? fv * c_st[r] : 0.f) + iv * gv;
            c_st[r] = c;
            float h = ov * tanhf(c);
            u16 hb = f2bf(h);
            hbuf[(size_t)(t & 1) * CB * CH + (size_t)(b0 + b) * CH + j0 + j_l] = hb;
            hall[((size_t)(b0 + b) * CT + t) * CH + j0 + j_l] = hb;
        }

        // per-group 8-block barrier (skip after final step)
        if (t < CT - 1) {
            target += 8;
            __syncthreads();                 // drains vmcnt: h stores complete
            if (tid == 0) {
                __threadfence();             // agent release: L2 writeback
                __hip_atomic_fetch_add(&cnt[bc * 32], 1u,
                                       __ATOMIC_RELEASE, __HIP_MEMORY_SCOPE_AGENT);
                while (__hip_atomic_load(&cnt[bc * 32],
                                         __ATOMIC_ACQUIRE, __HIP_MEMORY_SCOPE_AGENT) < target)
                    __builtin_amdgcn_s_sleep(1);
            }
            __syncthreads();                 // broadcast barrier completion
        }
    }
}

// ---------------------------------------------------------------------------
extern "C" void kernel_launch(void* const* d_in, const int* in_sizes, int n_in,
                              void* d_out, int out_size, void* d_ws, size_t ws_size,
                              hipStream_t stream) {
    const float* features = (const float*)d_in[0];
    const int*   seqs     = (const int*)d_in[1];
    const float* W_in  = (const float*)d_in[3];
    const float* b_in  = (const float*)d_in[4];
    const float* emb   = (const float*)d_in[5];
    const float* W_ih  = (const float*)d_in[6];
    const float* W_hh  = (const float*)d_in[7];
    const float* b_ih  = (const float*)d_in[8];
    const float* b_hh  = (const float*)d_in[9];
    const float* W_out = (const float*)d_in[10];
    const float* b_out = (const float*)d_in[11];
    float* out = (float*)d_out;

    char* p = (char*)d_ws;
    unsigned* cnt = (unsigned*)p;  p += 512;                    // 4 counters, 128B apart
    float* xg    = (float*)p;  p += (size_t)CB * CT * CG * 4;   // 41.9 MB
    u16* seqb    = (u16*)p;    p += (size_t)CB * CT * CE * 2;   // 5.2 MB
    u16* hallb   = (u16*)p;    p += (size_t)CB * CT * CH * 2;   // 5.2 MB
    u16* hbufb   = (u16*)p;    p += (size_t)2 * CB * CH * 2;    // 256 KB
    u16* feab    = (u16*)p;    p += (size_t)CB * CF * 2;
    u16* winb    = (u16*)p;    p += (size_t)CE * CF * 2;
    u16* wihb    = (u16*)p;    p += (size_t)CG * CE * 2;
    u16* whhb    = (u16*)p;    p += (size_t)CG * CH * 2;
    u16* woutb   = (u16*)p;    p += (size_t)CVP * CE * 2;
    float* biasp = (float*)p;  p += (size_t)CG * 4;

    // --- prep: conversions + counter zeroing ---
    zero_cnt<<<1, 128, 0, stream>>>(cnt);
    cvt_bf16<<<192, 256, 0, stream>>>(features, feab, CB * CF / 4);
    cvt_bf16<<<768, 256, 0, stream>>>(W_in, winb, CE * CF / 4);
    cvt_bf16<<<1024, 256, 0, stream>>>(W_ih, wihb, CG * CE / 4);
    cvt_bf16<<<1024, 256, 0, stream>>>(W_hh, whhb, CG * CH / 4);
    cvt_wout<<<2048, 256, 0, stream>>>(W_out, woutb);
    bias_sum<<<8, 256, 0, stream>>>(b_ih, b_hh, biasp);

    // --- seq assembly ---
    gather_emb<<<dim3(CT - 1, CB), 128, 0, stream>>>(seqs, emb, seqb);
    x0_kernel<<<dim3(8, 8), 256, 0, stream>>>(feab, winb, b_in, seqb);

    // --- xg = seq @ W_ih^T + (b_ih+b_hh)  [5120 x 2048], fp32 out ---
    gemm_bf16<<<dim3(CG / 128, CB * CT / 128), 256, 0, stream>>>(
        seqb, CE, wihb, CE, biasp, xg, CG, CE, CG);

    // --- LSTM scan (persistent, 32 blocks, flag-sync) ---
    {
        const float* xg_c = xg;  const u16* whh_c = whhb;
        u16* hb_c = hbufb;       u16* ha_c = hallb;
        unsigned* cnt_c = cnt;
        void* args[] = {(void*)&xg_c, (void*)&whh_c, (void*)&hb_c, (void*)&ha_c,
                        (void*)&cnt_c};
        hipLaunchCooperativeKernel((void*)lstm_kernel, dim3(32), dim3(512),
                                   args, 0, stream);
    }

    // --- logits = h_all @ W_out^T + b_out  [5120 x 10000] ---
    gemm_bf16<<<dim3(CVP / 128, CB * CT / 128), 256, 0, stream>>>(
        hallb, CH, woutb, CH, b_out, out, CV, CH, CV);
}

// Round 5
// 595.028 us; speedup vs baseline: 5.2557x; 1.1673x over previous
//
#include <hip/hip_runtime.h>
#include <hip/hip_cooperative_groups.h>

#define CB 128     // batch
#define CF 1536    // feature
#define CE 512     // embed
#define CH 512     // hidden
#define CG 2048    // 4*H (q-major: gate q = rows q*512..q*512+511)
#define CV 10000   // vocab
#define CVP 10112  // vocab padded to 79*128
#define CT 40      // max len

typedef unsigned short u16;
typedef __attribute__((ext_vector_type(8))) short bf16x8;
typedef __attribute__((ext_vector_type(4))) float f32x4;

#define MFMA16(a, b, c) __builtin_amdgcn_mfma_f32_16x16x32_bf16(a, b, c, 0, 0, 0)

__device__ __forceinline__ u16 f2bf(float x) {
    unsigned u = __float_as_uint(x);
    u += 0x7FFFu + ((u >> 16) & 1u);          // RNE (finite values only here)
    return (u16)(u >> 16);
}

__device__ __forceinline__ void gload_lds16(const void* g, void* l) {
    __builtin_amdgcn_global_load_lds(
        (const __attribute__((address_space(1))) unsigned int*)g,
        (__attribute__((address_space(3))) unsigned int*)l, 16, 0, 0);
}

__device__ __forceinline__ float sigm(float x) { return 1.f / (1.f + expf(-x)); }

// ---------------------------------------------------------------------------
// Fused prep: bf16 conversions (features, W_in, W_ih, W_hh), bias sum,
// barrier-counter zeroing. Grid-stride over float4 chunks.
// ---------------------------------------------------------------------------
__device__ __forceinline__ void cvt4(const float* s, u16* d, int i) {
    float4 v = ((const float4*)s)[i];
    ((ushort4*)d)[i] = make_ushort4(f2bf(v.x), f2bf(v.y), f2bf(v.z), f2bf(v.w));
}

__global__ void prep_all(const float* __restrict__ fea, const float* __restrict__ win,
                         const float* __restrict__ wih, const float* __restrict__ whh,
                         const float* __restrict__ bih, const float* __restrict__ bhh,
                         u16* __restrict__ feab, u16* __restrict__ winb,
                         u16* __restrict__ wihb, u16* __restrict__ whhb,
                         float* __restrict__ biasp, unsigned* __restrict__ cnt) {
    if (blockIdx.x == 0 && threadIdx.x < 256) cnt[threadIdx.x] = 0;
    const int N0 = CB * CF / 4;            // 49152
    const int N1 = N0 + CE * CF / 4;       // +196608
    const int N2 = N1 + CG * CE / 4;       // +262144
    const int N3 = N2 + CG * CH / 4;       // +262144
    const int N4 = N3 + CG / 4;            // +512
    int i = blockIdx.x * blockDim.x + threadIdx.x;
    for (; i < N4; i += gridDim.x * blockDim.x) {
        if (i < N0) cvt4(fea, feab, i);
        else if (i < N1) cvt4(win, winb, i - N0);
        else if (i < N2) cvt4(wih, wihb, i - N1);
        else if (i < N3) cvt4(whh, whhb, i - N2);
        else {
            int e = (i - N3) * 4;
#pragma unroll
            for (int k = 0; k < 4; ++k) biasp[e + k] = bih[e + k] + bhh[e + k];
        }
    }
}

// W_out [CV][CE] fp32 -> [CVP][CE] bf16, zero-padded rows
__global__ void cvt_wout(const float* __restrict__ s, u16* __restrict__ d) {
    const int n4 = CVP * CE / 4;
    int i = blockIdx.x * blockDim.x + threadIdx.x;
    for (; i < n4; i += gridDim.x * blockDim.x) {
        int e = i * 4;
        int row = e >> 9;           // /512
        int col = e & 511;
        ushort4 o;
        if (row < CV) {
            float4 v = *(const float4*)(s + (size_t)row * CE + col);
            o = make_ushort4(f2bf(v.x), f2bf(v.y), f2bf(v.z), f2bf(v.w));
        } else {
            o = make_ushort4(0, 0, 0, 0);
        }
        ((ushort4*)d)[i] = o;
    }
}

// ---------------------------------------------------------------------------
// seq[b, 1+t, :] = bf16(emb[seqs[b,t], :])
// ---------------------------------------------------------------------------
__global__ void gather_emb(const int* __restrict__ seqs, const float* __restrict__ emb,
                           u16* __restrict__ seq) {
    int t = blockIdx.x;            // 0..38
    int b = blockIdx.y;            // 0..127
    int tok = seqs[b * (CT - 1) + t];
    float4 v = ((const float4*)(emb + (size_t)tok * CE))[threadIdx.x];
    ushort4 o = make_ushort4(f2bf(v.x), f2bf(v.y), f2bf(v.z), f2bf(v.w));
    *(ushort4*)(seq + ((size_t)b * CT + 1 + t) * CE + threadIdx.x * 4) = o;
}

// ---------------------------------------------------------------------------
// x0 = features @ W_in^T + b_in -> bf16 into seq[:,0,:]
// ---------------------------------------------------------------------------
__global__ __launch_bounds__(256)
void x0_kernel(const u16* __restrict__ fea, const u16* __restrict__ win,
               const float* __restrict__ b_in, u16* __restrict__ seq) {
    const int tid = threadIdx.x, lane = tid & 63, w = tid >> 6;
    const int m0 = blockIdx.y * 16, n0 = blockIdx.x * 64;
    const int r16 = lane & 15, koff = lane >> 4;
    const u16* ap = fea + (size_t)(m0 + r16) * CF + koff * 8;
    const u16* bp = win + (size_t)(n0 + w * 16 + r16) * CF + koff * 8;
    f32x4 acc0 = {0.f, 0.f, 0.f, 0.f}, acc1 = {0.f, 0.f, 0.f, 0.f};
#pragma unroll
    for (int ks = 0; ks < 48; ++ks) {
        bf16x8 af = *(const bf16x8*)(ap + ks * 32);
        bf16x8 bf = *(const bf16x8*)(bp + ks * 32);
        if (ks & 1) acc1 = MFMA16(af, bf, acc1);
        else        acc0 = MFMA16(af, bf, acc0);
    }
    const int col = n0 + w * 16 + r16;
    const float bb = b_in[col];
#pragma unroll
    for (int r = 0; r < 4; ++r) {
        int brow = m0 + koff * 4 + r;
        seq[(size_t)brow * (CT * CE) + col] = f2bf(acc0[r] + acc1[r] + bb);
    }
}

// ---------------------------------------------------------------------------
// bf16 MFMA GEMM: C[M,N] = A[M,K] @ B[N,K]^T + bias (fp32 out)
// 128x128 tile, BK=32, 4 waves 2x2 (64x64/wave, 4x4 frags of 16x16x32).
// XCD-aware block swizzle (grid size must be divisible by 8 — both call
// sites are: 640 and 3160).
// ---------------------------------------------------------------------------
__global__ __launch_bounds__(256)
void gemm_bf16(const u16* __restrict__ A, int lda, const u16* __restrict__ B, int ldb,
               const float* __restrict__ bias, float* __restrict__ C, int ldc,
               int K, int Nvalid) {
    __shared__ __align__(16) u16 As[4096];   // [128 rows][32 k] bf16, 64B rows
    __shared__ __align__(16) u16 Bs[4096];
    const int tid = threadIdx.x, lane = tid & 63;
    const int wid = tid >> 6, wm = wid >> 1, wn = wid & 1;
    // XCD swizzle: contiguous tile chunk per XCD (round-robin dispatch assumed;
    // perf heuristic only, correctness independent of mapping)
    const int nwg = gridDim.x * gridDim.y;
    const int orig = blockIdx.y * gridDim.x + blockIdx.x;
    const int swz = (orig & 7) * (nwg >> 3) + (orig >> 3);
    const int m0 = (swz / gridDim.x) * 128, n0 = (swz % gridDim.x) * 128;
    const int r16 = lane & 15, koff = lane >> 4;

    f32x4 acc[4][4];
#pragma unroll
    for (int i = 0; i < 4; ++i)
#pragma unroll
        for (int j = 0; j < 4; ++j) acc[i][j] = (f32x4){0.f, 0.f, 0.f, 0.f};

    for (int k0 = 0; k0 < K; k0 += 32) {
#pragma unroll
        for (int c = 0; c < 2; ++c) {
            int flat = c * 4096 + tid * 16;          // byte offset in tile
            int row = flat >> 6;
            int phys = (flat >> 4) & 3;
            int logi = phys ^ ((row >> 1) & 3);
            gload_lds16(A + (size_t)(m0 + row) * lda + k0 + logi * 8, (char*)As + flat);
            gload_lds16(B + (size_t)(n0 + row) * ldb + k0 + logi * 8, (char*)Bs + flat);
        }
        __syncthreads();
        bf16x8 a[4], b[4];
#pragma unroll
        for (int i = 0; i < 4; ++i) {
            int row = wm * 64 + i * 16 + r16;
            int phys = koff ^ ((row >> 1) & 3);
            a[i] = *(const bf16x8*)((const char*)As + row * 64 + phys * 16);
        }
#pragma unroll
        for (int j = 0; j < 4; ++j) {
            int row = wn * 64 + j * 16 + r16;
            int phys = koff ^ ((row >> 1) & 3);
            b[j] = *(const bf16x8*)((const char*)Bs + row * 64 + phys * 16);
        }
#pragma unroll
        for (int i = 0; i < 4; ++i)
#pragma unroll
            for (int j = 0; j < 4; ++j) acc[i][j] = MFMA16(a[i], b[j], acc[i][j]);
        __syncthreads();
    }

#pragma unroll
    for (int j = 0; j < 4; ++j) {
        int col = n0 + wn * 64 + j * 16 + r16;
        bool ok = col < Nvalid;
        float bj = ok ? bias[col] : 0.f;
#pragma unroll
        for (int i = 0; i < 4; ++i) {
            int rowb = m0 + wm * 64 + i * 16 + koff * 4;
#pragma unroll
            for (int r = 0; r < 4; ++r)
                if (ok) C[(size_t)(rowb + r) * ldc + col] = acc[i][j][r] + bj;
        }
    }
}

// ---------------------------------------------------------------------------
// Persistent LSTM scan: 64 blocks = 8 batch-groups (16 rows) x 8 unit-blocks
// (64 units). Group = blockIdx&7 so a group's 8 blocks co-reside on one XCD
// under round-robin dispatch (locality heuristic; sync is device-scope).
// 512 threads (8 waves): wave w -> unit slice s=w&3 (16 units), gate pair
// gp=w>>2 (gates gp*2, gp*2+1). W_hh slice (256 KB) register-resident
// (launch_bounds(512,2) -> 256 VGPR budget). One flag barrier per step;
// relaxed spin + final acquire load.
// ---------------------------------------------------------------------------
__global__ __launch_bounds__(512, 2)
void lstm_kernel(const float* __restrict__ xg,   // [B,T,G] fp32, q-major, bias folded
                 const u16* __restrict__ Whh,    // [G,H] bf16, q-major rows
                 u16* __restrict__ hbuf,         // [2,B,H] bf16
                 u16* __restrict__ hall,         // [B,T,H] bf16
                 unsigned* __restrict__ cnt)     // [8] stride-32, zeroed
{
    __shared__ __align__(16) u16 Hs[16 * 512];   // 16 rows x 1KB, slot-swizzled
    __shared__ float gS[4][16][68];

    const int tid = threadIdx.x, lane = tid & 63, w = tid >> 6;
    const int bc = blockIdx.x & 7, nc = blockIdx.x >> 3;
    const int b0 = bc * 16, j0 = nc * 64;
    const int s = w & 3, gp = w >> 2;
    const int r16 = lane & 15, koff = lane >> 4;
    const int j_l = tid & 63;            // elementwise: unit within slice
    const int bw = tid >> 6;             // elementwise: rows bw*2..+1

    // W_hh fragments resident in registers: wf[gate-of-pair][k-step], 128 VGPRs
    bf16x8 wf[2][16];
#pragma unroll
    for (int gq = 0; gq < 2; ++gq) {
        const u16* wrow =
            Whh + (size_t)((gp * 2 + gq) * CH + j0 + s * 16 + r16) * CH + koff * 8;
#pragma unroll
        for (int ks = 0; ks < 16; ++ks) wf[gq][ks] = *(const bf16x8*)(wrow + ks * 32);
    }

    float c_st[2] = {0.f, 0.f};
    unsigned target = 0;

    for (int t = 0; t < CT; ++t) {
        // xg prefetch for the fused elementwise (256B coalesced per (b,q))
        float xq[4][2];
#pragma unroll
        for (int q = 0; q < 4; ++q)
#pragma unroll
            for (int r = 0; r < 2; ++r)
                xq[q][r] = xg[((size_t)(b0 + bw * 2 + r) * CT + t) * CG + q * CH + j0 + j_l];

        if (t > 0) {
            const u16* hprev = hbuf + (size_t)((t - 1) & 1) * CB * CH;
            // stage h [16][512] bf16 (16KB), swizzled source -> linear LDS
#pragma unroll
            for (int c = 0; c < 2; ++c) {
                int flat = c * 8192 + tid * 16;     // byte
                int row = flat >> 10;               // 0..15 (wave-uniform)
                int phys = (flat >> 4) & 63;        // = lane
                int logi = phys ^ (row & 7);
                gload_lds16(hprev + (size_t)(b0 + row) * CH + logi * 8, (char*)Hs + flat);
            }
            __syncthreads();

            f32x4 acc[2] = {(f32x4){0.f, 0.f, 0.f, 0.f}, (f32x4){0.f, 0.f, 0.f, 0.f}};
#pragma unroll
            for (int ks = 0; ks < 16; ++ks) {
                int ph = (ks * 4 + koff) ^ (r16 & 7);
                bf16x8 a = *(const bf16x8*)((const char*)Hs + r16 * 1024 + ph * 16);
                acc[0] = MFMA16(a, wf[0][ks], acc[0]);
                acc[1] = MFMA16(a, wf[1][ks], acc[1]);
            }
            // exchange gate sums via LDS (C/D: row=batch koff*4+r, col=unit r16)
#pragma unroll
            for (int gq = 0; gq < 2; ++gq)
#pragma unroll
                for (int r = 0; r < 4; ++r)
                    gS[gp * 2 + gq][koff * 4 + r][s * 16 + r16] = acc[gq][r];
            __syncthreads();
        }

        // fused elementwise: 2 batch rows per thread, unit j_l
#pragma unroll
        for (int r = 0; r < 2; ++r) {
            int b = bw * 2 + r;
            float gi = xq[0][r], gf = xq[1][r], gg = xq[2][r], go = xq[3][r];
            if (t > 0) {
                gi += gS[0][b][j_l]; gf += gS[1][b][j_l];
                gg += gS[2][b][j_l]; go += gS[3][b][j_l];
            }
            float iv = sigm(gi), fv = sigm(gf), gv = tanhf(gg), ov = sigm(go);
            float c = (t > 0 ? fv * c_st[r] : 0.f) + iv * gv;
            c_st[r] = c;
            float h = ov * tanhf(c);
            u16 hb = f2bf(h);
            hbuf[(size_t)(t & 1) * CB * CH + (size_t)(b0 + b) * CH + j0 + j_l] = hb;
            hall[((size_t)(b0 + b) * CT + t) * CH + j0 + j_l] = hb;
        }

        // per-group 8-block barrier (skip after final step)
        if (t < CT - 1) {
            target += 8;
            __syncthreads();                 // drains vmcnt: h stores complete
            if (tid == 0) {
                __hip_atomic_fetch_add(&cnt[bc * 32], 1u,
                                       __ATOMIC_RELEASE, __HIP_MEMORY_SCOPE_AGENT);
                while (__hip_atomic_load(&cnt[bc * 32],
                                         __ATOMIC_RELAXED, __HIP_MEMORY_SCOPE_AGENT) < target)
                    __builtin_amdgcn_s_sleep(1);
                (void)__hip_atomic_load(&cnt[bc * 32],
                                        __ATOMIC_ACQUIRE, __HIP_MEMORY_SCOPE_AGENT);
            }
            __syncthreads();                 // broadcast barrier completion
        }
    }
}

// ---------------------------------------------------------------------------
extern "C" void kernel_launch(void* const* d_in, const int* in_sizes, int n_in,
                              void* d_out, int out_size, void* d_ws, size_t ws_size,
                              hipStream_t stream) {
    const float* features = (const float*)d_in[0];
    const int*   seqs     = (const int*)d_in[1];
    const float* W_in  = (const float*)d_in[3];
    const float* b_in  = (const float*)d_in[4];
    const float* emb   = (const float*)d_in[5];
    const float* W_ih  = (const float*)d_in[6];
    const float* W_hh  = (const float*)d_in[7];
    const float* b_ih  = (const float*)d_in[8];
    const float* b_hh  = (const float*)d_in[9];
    const float* W_out = (const float*)d_in[10];
    const float* b_out = (const float*)d_in[11];
    float* out = (float*)d_out;

    char* p = (char*)d_ws;
    unsigned* cnt = (unsigned*)p;  p += 1024;                   // 8 counters, 128B apart
    float* xg    = (float*)p;  p += (size_t)CB * CT * CG * 4;   // 41.9 MB
    u16* seqb    = (u16*)p;    p += (size_t)CB * CT * CE * 2;   // 5.2 MB
    u16* hallb   = (u16*)p;    p += (size_t)CB * CT * CH * 2;   // 5.2 MB
    u16* hbufb   = (u16*)p;    p += (size_t)2 * CB * CH * 2;    // 256 KB
    u16* feab    = (u16*)p;    p += (size_t)CB * CF * 2;
    u16* winb    = (u16*)p;    p += (size_t)CE * CF * 2;
    u16* wihb    = (u16*)p;    p += (size_t)CG * CE * 2;
    u16* whhb    = (u16*)p;    p += (size_t)CG * CH * 2;
    u16* woutb   = (u16*)p;    p += (size_t)CVP * CE * 2;
    float* biasp = (float*)p;  p += (size_t)CG * 4;

    // --- fused prep (conversions + bias + counter zero) ---
    prep_all<<<2048, 256, 0, stream>>>(features, W_in, W_ih, W_hh, b_ih, b_hh,
                                       feab, winb, wihb, whhb, biasp, cnt);
    cvt_wout<<<2048, 256, 0, stream>>>(W_out, woutb);

    // --- seq assembly ---
    gather_emb<<<dim3(CT - 1, CB), 128, 0, stream>>>(seqs, emb, seqb);
    x0_kernel<<<dim3(8, 8), 256, 0, stream>>>(feab, winb, b_in, seqb);

    // --- xg = seq @ W_ih^T + (b_ih+b_hh)  [5120 x 2048], fp32 out ---
    gemm_bf16<<<dim3(CG / 128, CB * CT / 128), 256, 0, stream>>>(
        seqb, CE, wihb, CE, biasp, xg, CG, CE, CG);

    // --- LSTM scan (persistent, 64 blocks, XCD-local groups, flag-sync) ---
    {
        const float* xg_c = xg;  const u16* whh_c = whhb;
        u16* hb_c = hbufb;       u16* ha_c = hallb;
        unsigned* cnt_c = cnt;
        void* args[] = {(void*)&xg_c, (void*)&whh_c, (void*)&hb_c, (void*)&ha_c,
                        (void*)&cnt_c};
        hipLaunchCooperativeKernel((void*)lstm_kernel, dim3(64), dim3(512),
                                   args, 0, stream);
    }

    // --- logits = h_all @ W_out^T + b_out  [5120 x 10000] ---
    gemm_bf16<<<dim3(CVP / 128, CB * CT / 128), 256, 0, stream>>>(
        hallb, CH, woutb, CH, b_out, out, CV, CH, CV);
}